// Round 1
// baseline (1384.349 us; speedup 1.0000x reference)
//
#include <hip/hip_runtime.h>
#include <hip/hip_bf16.h>
#include <math.h>

#define B_    4
#define S_    2048
#define D_    1024
#define H_    8
#define N_    16
#define HN_   128
#define L_    2
#define DFF_  4096
#define C_    1024
#define MTOK  8192   // B_*S_

using bf16 = __hip_bfloat16;
typedef __attribute__((ext_vector_type(8))) short  short8;
typedef __attribute__((ext_vector_type(4))) float  f32x4;

static __device__ __forceinline__ float sigmoidf_(float x) { return 1.f / (1.f + expf(-x)); }

static __device__ __forceinline__ unsigned short f2bf_bits(float f) {
    bf16 h = __float2bfloat16(f);
    return __builtin_bit_cast(unsigned short, h);
}

// ---------------------------------------------------------------------------
// Weight transpose + convert: src f32 [K][N] -> dst bf16 [N][K]
// ---------------------------------------------------------------------------
__global__ __launch_bounds__(256) void transpose_k(const float* __restrict__ src,
                                                   bf16* __restrict__ dst,
                                                   int K, int N) {
    __shared__ float t[32][33];
    int n0 = blockIdx.x * 32, k0 = blockIdx.y * 32;
    int tx = threadIdx.x, ty = threadIdx.y;
    #pragma unroll
    for (int i = ty; i < 32; i += 8)
        t[i][tx] = src[(size_t)(k0 + i) * N + n0 + tx];
    __syncthreads();
    #pragma unroll
    for (int i = ty; i < 32; i += 8)
        dst[(size_t)(n0 + i) * K + k0 + tx] = __float2bfloat16(t[tx][i]);
}

// ---------------------------------------------------------------------------
// Embedding: h[tok] = emb[x[tok]] + pos_emb[tok % S]
// ---------------------------------------------------------------------------
__global__ __launch_bounds__(256) void embed_k(const int* __restrict__ x,
                                               const float* __restrict__ emb,
                                               const float* __restrict__ pos,
                                               float* __restrict__ h) {
    int tok = blockIdx.x, t = threadIdx.x;
    int id = x[tok];
    int s  = tok & (S_ - 1);
    float4 a = ((const float4*)(emb + (size_t)id * D_))[t];
    float4 p = ((const float4*)(pos + (size_t)s * D_))[t];
    float4 r; r.x = a.x + p.x; r.y = a.y + p.y; r.z = a.z + p.z; r.w = a.w + p.w;
    ((float4*)(h + (size_t)tok * D_))[t] = r;
}

// ---------------------------------------------------------------------------
// LayerNorm (row=1024) -> bf16 output
// ---------------------------------------------------------------------------
__global__ __launch_bounds__(256) void ln_k(const float* __restrict__ x,
                                            const float* __restrict__ g,
                                            const float* __restrict__ be,
                                            bf16* __restrict__ out) {
    int row = blockIdx.x, t = threadIdx.x;
    float4 v = ((const float4*)(x + (size_t)row * D_))[t];
    float s  = v.x + v.y + v.z + v.w;
    float sq = v.x * v.x + v.y * v.y + v.z * v.z + v.w * v.w;
    #pragma unroll
    for (int o = 32; o > 0; o >>= 1) {
        s  += __shfl_down(s, o);
        sq += __shfl_down(sq, o);
    }
    __shared__ float red[8];
    __shared__ float mv[2];
    int wave = t >> 6, lane = t & 63;
    if (lane == 0) { red[wave] = s; red[4 + wave] = sq; }
    __syncthreads();
    if (t == 0) {
        float S0 = red[0] + red[1] + red[2] + red[3];
        float Q  = red[4] + red[5] + red[6] + red[7];
        float m  = S0 * (1.f / 1024.f);
        float var = Q * (1.f / 1024.f) - m * m;
        mv[0] = m; mv[1] = rsqrtf(var + 1e-5f);
    }
    __syncthreads();
    float m = mv[0], rs = mv[1];
    float4 gg = ((const float4*)g)[t];
    float4 bb = ((const float4*)be)[t];
    ushort4 o;
    o.x = f2bf_bits((v.x - m) * rs * gg.x + bb.x);
    o.y = f2bf_bits((v.y - m) * rs * gg.y + bb.y);
    o.z = f2bf_bits((v.z - m) * rs * gg.z + bb.z);
    o.w = f2bf_bits((v.w - m) * rs * gg.w + bb.w);
    ((ushort4*)(out + (size_t)row * D_))[t] = o;
}

// ---------------------------------------------------------------------------
// SSM scan. ab: f32 [MTOK][256] (cols 0..127 = alpha post-sigmoid, 128..255 = b)
// hs: bf16 [MTOK][128]. One block per (b,h); thread = chunk(0..15)*16 + n(0..15).
// ---------------------------------------------------------------------------
__global__ __launch_bounds__(256) void ssm_scan_k(const float* __restrict__ ab,
                                                  bf16* __restrict__ hs) {
    const int CL = S_ / 16;  // 128 steps per chunk
    int bh = blockIdx.x;
    int b = bh >> 3, hh = bh & 7;
    int t = threadIdx.x;
    int chunk = t >> 4, n = t & 15;
    size_t rowbase = (size_t)b * S_ + (size_t)chunk * CL;
    const float* ap = ab + rowbase * 256 + hh * 16 + n;
    const float* bp = ap + 128;

    // pass 1: composed op over this chunk: h_out = A*h_in + Bc
    float A = 1.f, Bc = 0.f;
    for (int i = 0; i < CL; i++) {
        float a = ap[(size_t)i * 256], bv = bp[(size_t)i * 256];
        A *= a; Bc = a * Bc + bv;
    }
    __shared__ float sA[16][16], sB[16][16], sH[16][16];
    sA[chunk][n] = A; sB[chunk][n] = Bc;
    __syncthreads();
    if (t < 16) {  // thread t owns chain n=t: prefix over chunks
        float run = 0.f;
        #pragma unroll
        for (int c = 0; c < 16; c++) {
            sH[c][t] = run;
            run = sA[c][t] * run + sB[c][t];
        }
    }
    __syncthreads();
    // pass 2: rescan with correct h_init, write out
    float hrun = sH[chunk][n];
    bf16* op = hs + rowbase * 128 + hh * 16 + n;
    for (int i = 0; i < CL; i++) {
        float a = ap[(size_t)i * 256], bv = bp[(size_t)i * 256];
        hrun = a * hrun + bv;
        op[(size_t)i * 128] = __float2bfloat16(hrun);
    }
}

// ---------------------------------------------------------------------------
// bf16 MFMA GEMM: C[M,N] = A[M,K] @ W^T  (W stored [N][K] bf16, pre-transposed)
// 128x128 tile, BK=64, 4 waves, 16x16x32 MFMA, fp32 accum, fused epilogues.
// ---------------------------------------------------------------------------
enum { EP_AB = 0, EP_BIAS_RES = 1, EP_BIAS_BF16 = 2, EP_SILUMUL_BF16 = 3,
       EP_GELU_BF16 = 4, EP_BIAS_F32 = 5 };

#define GLOAD_LDS(gp, lp) \
    __builtin_amdgcn_global_load_lds((__attribute__((address_space(1))) void*)(gp), \
                                     (__attribute__((address_space(3))) void*)(lp), 16, 0, 0)

template <int EP>
__global__ __launch_bounds__(256) void gemm_k(
    const bf16* __restrict__ A, const bf16* __restrict__ W,
    float* __restrict__ outF, bf16* __restrict__ outB,
    const float* __restrict__ b1, const float* __restrict__ b2,
    const float* __restrict__ resF, const bf16* __restrict__ resB,
    int M, int N, int K) {
    __shared__ __align__(16) bf16 As[128 * 64];
    __shared__ __align__(16) bf16 Bs[128 * 64];
    const int tid = threadIdx.x;
    const int wave = tid >> 6, lane = tid & 63;
    const int bm = blockIdx.x * 128, bn = blockIdx.y * 128;
    const int wr = (wave >> 1) * 64, wc = (wave & 1) * 64;

    f32x4 acc[4][4];
    #pragma unroll
    for (int m = 0; m < 4; m++)
        #pragma unroll
        for (int n = 0; n < 4; n++) acc[m][n] = f32x4{0.f, 0.f, 0.f, 0.f};

    const int srow = tid >> 3;        // 0..31
    const int skc  = (tid & 7) * 8;   // k-chunk (elements)

    for (int k0 = 0; k0 < K; k0 += 64) {
        #pragma unroll
        for (int rr = 0; rr < 4; rr++) {
            int row = rr * 32 + srow;
            GLOAD_LDS(A + (size_t)(bm + row) * K + k0 + skc, As + row * 64 + skc);
            GLOAD_LDS(W + (size_t)(bn + row) * K + k0 + skc, Bs + row * 64 + skc);
        }
        __syncthreads();
        #pragma unroll
        for (int ks = 0; ks < 2; ks++) {
            const int kb = ks * 32 + (lane >> 4) * 8;
            short8 af[4], bfr[4];
            #pragma unroll
            for (int m = 0; m < 4; m++)
                af[m] = *reinterpret_cast<const short8*>(As + (wr + m * 16 + (lane & 15)) * 64 + kb);
            #pragma unroll
            for (int n = 0; n < 4; n++)
                bfr[n] = *reinterpret_cast<const short8*>(Bs + (wc + n * 16 + (lane & 15)) * 64 + kb);
            #pragma unroll
            for (int m = 0; m < 4; m++)
                #pragma unroll
                for (int n = 0; n < 4; n++)
                    acc[m][n] = __builtin_amdgcn_mfma_f32_16x16x32_bf16(af[m], bfr[n], acc[m][n], 0, 0, 0);
        }
        __syncthreads();
    }

    const int cb = bn + wc + (lane & 15);
    const int rb = bm + wr + (lane >> 4) * 4;
    #pragma unroll
    for (int m = 0; m < 4; m++) {
        #pragma unroll
        for (int n = 0; n < 4; n++) {
            int col = cb + n * 16;
            #pragma unroll
            for (int i = 0; i < 4; i++) {
                int row = rb + m * 16 + i;
                size_t idx = (size_t)row * N + col;
                float v = acc[m][n][i];
                if constexpr (EP == EP_AB) {
                    if (col < HN_) v = sigmoidf_(v + b1[col]);
                    else           v = v + b2[col - HN_];
                    outF[idx] = v;
                } else if constexpr (EP == EP_BIAS_RES) {
                    outF[idx] = v + b1[col] + resF[idx];
                } else if constexpr (EP == EP_BIAS_BF16) {
                    outB[idx] = __float2bfloat16(v + b1[col]);
                } else if constexpr (EP == EP_SILUMUL_BF16) {
                    float c1 = __bfloat162float(resB[idx]);
                    float sil = c1 * sigmoidf_(c1);
                    outB[idx] = __float2bfloat16((v + b1[col]) * sil);
                } else if constexpr (EP == EP_GELU_BF16) {
                    float xv = v + b1[col];
                    outB[idx] = __float2bfloat16(0.5f * xv * (1.f + erff(xv * 0.70710678118f)));
                } else {  // EP_BIAS_F32
                    outF[idx] = v + b1[col];
                }
            }
        }
    }
}

// ---------------------------------------------------------------------------
extern "C" void kernel_launch(void* const* d_in, const int* in_sizes, int n_in,
                              void* d_out, int out_size, void* d_ws, size_t ws_size,
                              hipStream_t stream) {
    const int*   x       = (const int*)  d_in[0];
    const float* emb     = (const float*)d_in[1];
    const float* pos_emb = (const float*)d_in[2];
    const float* alpha_W = (const float*)d_in[3];
    const float* alpha_b = (const float*)d_in[4];
    const float* in_W    = (const float*)d_in[5];
    const float* in_b    = (const float*)d_in[6];
    const float* out_W   = (const float*)d_in[7];
    const float* out_b   = (const float*)d_in[8];
    const float* ssm_g   = (const float*)d_in[9];
    const float* ssm_be  = (const float*)d_in[10];
    const float* w1_W    = (const float*)d_in[11];
    const float* w1_b    = (const float*)d_in[12];
    const float* w2_W    = (const float*)d_in[13];
    const float* w2_b    = (const float*)d_in[14];
    const float* w3_W    = (const float*)d_in[15];
    const float* w3_b    = (const float*)d_in[16];
    const float* ff_g    = (const float*)d_in[17];
    const float* ff_be   = (const float*)d_in[18];
    const float* on_g    = (const float*)d_in[19];
    const float* on_be   = (const float*)d_in[20];
    const float* h1_W    = (const float*)d_in[21];
    const float* h1_b    = (const float*)d_in[22];
    const float* h2_W    = (const float*)d_in[23];
    const float* h2_b    = (const float*)d_in[24];
    float* outp = (float*)d_out;
    (void)in_sizes; (void)n_in; (void)out_size; (void)ws_size;

    char* ws = (char*)d_ws;
    size_t off = 0;
    auto alloc = [&](size_t bytes) { size_t o = off; off += (bytes + 255) & ~(size_t)255; return o; };
    float* h    = (float*)(ws + alloc((size_t)MTOK * D_ * 4));
    bf16*  xn   = (bf16*) (ws + alloc((size_t)MTOK * D_ * 2));
    bf16*  abw  = (bf16*) (ws + alloc((size_t)L_ * 256 * D_ * 2));
    bf16*  outw = (bf16*) (ws + alloc((size_t)L_ * D_ * HN_ * 2));
    bf16*  w1w  = (bf16*) (ws + alloc((size_t)L_ * DFF_ * D_ * 2));
    bf16*  w3w  = (bf16*) (ws + alloc((size_t)L_ * DFF_ * D_ * 2));
    bf16*  w2w  = (bf16*) (ws + alloc((size_t)L_ * D_ * DFF_ * 2));
    bf16*  h1w  = (bf16*) (ws + alloc((size_t)2048 * D_ * 2));
    bf16*  h2w  = (bf16*) (ws + alloc((size_t)D_ * 2048 * 2));
    float* ab   = (float*)(ws + alloc((size_t)MTOK * 256 * 4));
    bf16*  hs   = (bf16*) (ws + alloc((size_t)MTOK * HN_ * 2));
    bf16*  c1   = (bf16*) (ws + alloc((size_t)MTOK * DFF_ * 2));  // also reused as head g1

    auto T = [&](const float* src, bf16* dst, int K, int N) {
        transpose_k<<<dim3(N / 32, K / 32), dim3(32, 8), 0, stream>>>(src, dst, K, N);
    };

    // weights -> bf16, transposed to [N][K]
    for (int l = 0; l < L_; l++) {
        T(alpha_W + (size_t)l * D_ * HN_,  abw + (size_t)l * 256 * D_,                 D_,  HN_);
        T(in_W    + (size_t)l * D_ * HN_,  abw + (size_t)l * 256 * D_ + (size_t)HN_ * D_, D_, HN_);
        T(out_W   + (size_t)l * HN_ * D_,  outw + (size_t)l * D_ * HN_,                HN_, D_);
        T(w1_W    + (size_t)l * D_ * DFF_, w1w + (size_t)l * DFF_ * D_,                D_,  DFF_);
        T(w3_W    + (size_t)l * D_ * DFF_, w3w + (size_t)l * DFF_ * D_,                D_,  DFF_);
        T(w2_W    + (size_t)l * DFF_ * D_, w2w + (size_t)l * D_ * DFF_,                DFF_, D_);
    }
    T(h1_W, h1w, D_, 2048);
    T(h2_W, h2w, 2048, D_);

    embed_k<<<MTOK, 256, 0, stream>>>(x, emb, pos_emb, h);

    for (int l = 0; l < L_; l++) {
        // ---- SSM block ----
        ln_k<<<MTOK, 256, 0, stream>>>(h, ssm_g + l * D_, ssm_be + l * D_, xn);
        gemm_k<EP_AB><<<dim3(64, 2), 256, 0, stream>>>(
            xn, abw + (size_t)l * 256 * D_, ab, nullptr,
            alpha_b + l * HN_, in_b + l * HN_, nullptr, nullptr, MTOK, 256, D_);
        ssm_scan_k<<<B_ * H_, 256, 0, stream>>>(ab, hs);
        gemm_k<EP_BIAS_RES><<<dim3(64, 8), 256, 0, stream>>>(
            hs, outw + (size_t)l * D_ * HN_, h, nullptr,
            out_b + l * D_, nullptr, h, nullptr, MTOK, D_, HN_);
        // ---- SwiGLU block ----
        ln_k<<<MTOK, 256, 0, stream>>>(h, ff_g + l * D_, ff_be + l * D_, xn);
        gemm_k<EP_BIAS_BF16><<<dim3(64, 32), 256, 0, stream>>>(
            xn, w1w + (size_t)l * DFF_ * D_, nullptr, c1,
            w1_b + l * DFF_, nullptr, nullptr, nullptr, MTOK, DFF_, D_);
        gemm_k<EP_SILUMUL_BF16><<<dim3(64, 32), 256, 0, stream>>>(
            xn, w3w + (size_t)l * DFF_ * D_, nullptr, c1,
            w3_b + l * DFF_, nullptr, nullptr, c1, MTOK, DFF_, D_);
        gemm_k<EP_BIAS_RES><<<dim3(64, 8), 256, 0, stream>>>(
            c1, w2w + (size_t)l * D_ * DFF_, h, nullptr,
            w2_b + l * D_, nullptr, h, nullptr, MTOK, D_, DFF_);
    }

    // ---- head ----
    ln_k<<<MTOK, 256, 0, stream>>>(h, on_g, on_be, xn);
    gemm_k<EP_GELU_BF16><<<dim3(64, 16), 256, 0, stream>>>(
        xn, h1w, nullptr, c1, h1_b, nullptr, nullptr, nullptr, MTOK, 2048, D_);
    gemm_k<EP_BIAS_F32><<<dim3(64, 8), 256, 0, stream>>>(
        c1, h2w, outp, nullptr, h2_b, nullptr, nullptr, nullptr, MTOK, C_, 2048);
}

// Round 3
// 1153.751 us; speedup vs baseline: 1.1999x; 1.1999x over previous
//
#include <hip/hip_runtime.h>
#include <hip/hip_bf16.h>
#include <math.h>

#define B_    4
#define S_    2048
#define D_    1024
#define H_    8
#define N_    16
#define HN_   128
#define L_    2
#define DFF_  4096
#define C_    1024
#define MTOK  8192   // B_*S_

using bf16 = __hip_bfloat16;
typedef __attribute__((ext_vector_type(8))) short  short8;
typedef __attribute__((ext_vector_type(4))) float  f32x4;

static __device__ __forceinline__ float sigmoidf_(float x) { return 1.f / (1.f + expf(-x)); }

static __device__ __forceinline__ unsigned short f2bf_bits(float f) {
    bf16 h = __float2bfloat16(f);
    return __builtin_bit_cast(unsigned short, h);
}

#define GLOAD_LDS(gp, lp) \
    __builtin_amdgcn_global_load_lds((__attribute__((address_space(1))) void*)(gp), \
                                     (__attribute__((address_space(3))) void*)(lp), 16, 0, 0)

#define VMCNT(n) asm volatile("s_waitcnt vmcnt(" #n ")" ::: "memory")
#define BARRIER() do { asm volatile("" ::: "memory"); __builtin_amdgcn_s_barrier(); \
                       asm volatile("" ::: "memory"); } while (0)

// ---------------------------------------------------------------------------
// Weight transpose + convert: src f32 [K][N] -> dst bf16 [N][K]
// ---------------------------------------------------------------------------
__global__ __launch_bounds__(256) void transpose_k(const float* __restrict__ src,
                                                   bf16* __restrict__ dst,
                                                   int K, int N) {
    __shared__ float t[32][33];
    int n0 = blockIdx.x * 32, k0 = blockIdx.y * 32;
    int tx = threadIdx.x, ty = threadIdx.y;
    #pragma unroll
    for (int i = ty; i < 32; i += 8)
        t[i][tx] = src[(size_t)(k0 + i) * N + n0 + tx];
    __syncthreads();
    #pragma unroll
    for (int i = ty; i < 32; i += 8)
        dst[(size_t)(n0 + i) * K + k0 + tx] = __float2bfloat16(t[tx][i]);
}

// ---------------------------------------------------------------------------
// Embedding
// ---------------------------------------------------------------------------
__global__ __launch_bounds__(256) void embed_k(const int* __restrict__ x,
                                               const float* __restrict__ emb,
                                               const float* __restrict__ pos,
                                               float* __restrict__ h) {
    int tok = blockIdx.x, t = threadIdx.x;
    int id = x[tok];
    int s  = tok & (S_ - 1);
    float4 a = ((const float4*)(emb + (size_t)id * D_))[t];
    float4 p = ((const float4*)(pos + (size_t)s * D_))[t];
    float4 r; r.x = a.x + p.x; r.y = a.y + p.y; r.z = a.z + p.z; r.w = a.w + p.w;
    ((float4*)(h + (size_t)tok * D_))[t] = r;
}

// ---------------------------------------------------------------------------
// LayerNorm (row=1024) -> bf16
// ---------------------------------------------------------------------------
__global__ __launch_bounds__(256) void ln_k(const float* __restrict__ x,
                                            const float* __restrict__ g,
                                            const float* __restrict__ be,
                                            bf16* __restrict__ out) {
    int row = blockIdx.x, t = threadIdx.x;
    float4 v = ((const float4*)(x + (size_t)row * D_))[t];
    float s  = v.x + v.y + v.z + v.w;
    float sq = v.x * v.x + v.y * v.y + v.z * v.z + v.w * v.w;
    #pragma unroll
    for (int o = 32; o > 0; o >>= 1) {
        s  += __shfl_down(s, o);
        sq += __shfl_down(sq, o);
    }
    __shared__ float red[8];
    __shared__ float mv[2];
    int wave = t >> 6, lane = t & 63;
    if (lane == 0) { red[wave] = s; red[4 + wave] = sq; }
    __syncthreads();
    if (t == 0) {
        float S0 = red[0] + red[1] + red[2] + red[3];
        float Q  = red[4] + red[5] + red[6] + red[7];
        float m  = S0 * (1.f / 1024.f);
        float var = Q * (1.f / 1024.f) - m * m;
        mv[0] = m; mv[1] = rsqrtf(var + 1e-5f);
    }
    __syncthreads();
    float m = mv[0], rs = mv[1];
    float4 gg = ((const float4*)g)[t];
    float4 bb = ((const float4*)be)[t];
    ushort4 o;
    o.x = f2bf_bits((v.x - m) * rs * gg.x + bb.x);
    o.y = f2bf_bits((v.y - m) * rs * gg.y + bb.y);
    o.z = f2bf_bits((v.z - m) * rs * gg.z + bb.z);
    o.w = f2bf_bits((v.w - m) * rs * gg.w + bb.w);
    ((ushort4*)(out + (size_t)row * D_))[t] = o;
}

// ---------------------------------------------------------------------------
// SSM scan
// ---------------------------------------------------------------------------
__global__ __launch_bounds__(256) void ssm_scan_k(const float* __restrict__ ab,
                                                  bf16* __restrict__ hs) {
    const int CL = S_ / 16;
    int bh = blockIdx.x;
    int b = bh >> 3, hh = bh & 7;
    int t = threadIdx.x;
    int chunk = t >> 4, n = t & 15;
    size_t rowbase = (size_t)b * S_ + (size_t)chunk * CL;
    const float* ap = ab + rowbase * 256 + hh * 16 + n;
    const float* bp = ap + 128;

    float A = 1.f, Bc = 0.f;
    for (int i = 0; i < CL; i++) {
        float a = ap[(size_t)i * 256], bv = bp[(size_t)i * 256];
        A *= a; Bc = a * Bc + bv;
    }
    __shared__ float sA[16][16], sB[16][16], sH[16][16];
    sA[chunk][n] = A; sB[chunk][n] = Bc;
    __syncthreads();
    if (t < 16) {
        float run = 0.f;
        #pragma unroll
        for (int c = 0; c < 16; c++) {
            sH[c][t] = run;
            run = sA[c][t] * run + sB[c][t];
        }
    }
    __syncthreads();
    float hrun = sH[chunk][n];
    bf16* op = hs + rowbase * 128 + hh * 16 + n;
    for (int i = 0; i < CL; i++) {
        float a = ap[(size_t)i * 256], bv = bp[(size_t)i * 256];
        hrun = a * hrun + bv;
        op[(size_t)i * 128] = __float2bfloat16(hrun);
    }
}

// ---------------------------------------------------------------------------
// Shared epilogue element-op
// ---------------------------------------------------------------------------
enum { EP_AB = 0, EP_BIAS_RES = 1, EP_BIAS_BF16 = 2, EP_SILUMUL_BF16 = 3,
       EP_GELU_BF16 = 4, EP_BIAS_F32 = 5 };

template <int EP>
static __device__ __forceinline__ void ep_store(
    float v, size_t idx, int col,
    float* __restrict__ outF, bf16* __restrict__ outB,
    const float* __restrict__ b1, const float* __restrict__ b2,
    const float* __restrict__ resF, const bf16* __restrict__ resB) {
    if constexpr (EP == EP_AB) {
        if (col < HN_) v = sigmoidf_(v + b1[col]);
        else           v = v + b2[col - HN_];
        outF[idx] = v;
    } else if constexpr (EP == EP_BIAS_RES) {
        outF[idx] = v + b1[col] + resF[idx];
    } else if constexpr (EP == EP_BIAS_BF16) {
        outB[idx] = __float2bfloat16(v + b1[col]);
    } else if constexpr (EP == EP_SILUMUL_BF16) {
        float c1 = __bfloat162float(resB[idx]);
        float sil = c1 * sigmoidf_(c1);
        outB[idx] = __float2bfloat16((v + b1[col]) * sil);
    } else if constexpr (EP == EP_GELU_BF16) {
        float xv = v + b1[col];
        outB[idx] = __float2bfloat16(0.5f * xv * (1.f + erff(xv * 0.70710678118f)));
    } else {  // EP_BIAS_F32
        outF[idx] = v + b1[col];
    }
}

// ---------------------------------------------------------------------------
// 128x128 GEMM (m97 structure) — kept for small-N GEMMs (ab, out-proj)
// ---------------------------------------------------------------------------
template <int EP>
__global__ __launch_bounds__(256) void gemm_k(
    const bf16* __restrict__ A, const bf16* __restrict__ W,
    float* __restrict__ outF, bf16* __restrict__ outB,
    const float* __restrict__ b1, const float* __restrict__ b2,
    const float* __restrict__ resF, const bf16* __restrict__ resB,
    int M, int N, int K) {
    __shared__ __align__(16) bf16 As[128 * 64];
    __shared__ __align__(16) bf16 Bs[128 * 64];
    const int tid = threadIdx.x;
    const int wave = tid >> 6, lane = tid & 63;
    const int bm = blockIdx.x * 128, bn = blockIdx.y * 128;
    const int wr = (wave >> 1) * 64, wc = (wave & 1) * 64;

    f32x4 acc[4][4];
    #pragma unroll
    for (int m = 0; m < 4; m++)
        #pragma unroll
        for (int n = 0; n < 4; n++) acc[m][n] = f32x4{0.f, 0.f, 0.f, 0.f};

    const int srow = tid >> 3;
    const int skc  = (tid & 7) * 8;

    for (int k0 = 0; k0 < K; k0 += 64) {
        #pragma unroll
        for (int rr = 0; rr < 4; rr++) {
            int row = rr * 32 + srow;
            GLOAD_LDS(A + (size_t)(bm + row) * K + k0 + skc, As + row * 64 + skc);
            GLOAD_LDS(W + (size_t)(bn + row) * K + k0 + skc, Bs + row * 64 + skc);
        }
        __syncthreads();
        #pragma unroll
        for (int ks = 0; ks < 2; ks++) {
            const int kb = ks * 32 + (lane >> 4) * 8;
            short8 af[4], bfr[4];
            #pragma unroll
            for (int m = 0; m < 4; m++)
                af[m] = *reinterpret_cast<const short8*>(As + (wr + m * 16 + (lane & 15)) * 64 + kb);
            #pragma unroll
            for (int n = 0; n < 4; n++)
                bfr[n] = *reinterpret_cast<const short8*>(Bs + (wc + n * 16 + (lane & 15)) * 64 + kb);
            #pragma unroll
            for (int m = 0; m < 4; m++)
                #pragma unroll
                for (int n = 0; n < 4; n++)
                    acc[m][n] = __builtin_amdgcn_mfma_f32_16x16x32_bf16(af[m], bfr[n], acc[m][n], 0, 0, 0);
        }
        __syncthreads();
    }

    const int cb = bn + wc + (lane & 15);
    const int rb = bm + wr + (lane >> 4) * 4;
    #pragma unroll
    for (int m = 0; m < 4; m++)
        #pragma unroll
        for (int n = 0; n < 4; n++) {
            int col = cb + n * 16;
            #pragma unroll
            for (int i = 0; i < 4; i++) {
                int row = rb + m * 16 + i;
                ep_store<EP>(acc[m][n][i], (size_t)row * N + col, col,
                             outF, outB, b1, b2, resF, resB);
            }
        }
}

// ---------------------------------------------------------------------------
// 256xBN phase-split GEMM (T2 swizzle + T3/T4 counted-vmcnt + T5 setprio)
// 512 threads = 8 waves (2M x 4N). Per-wave output: 128 x (NR*16) where
// NR = BN/64 (BN=256 -> 128x64, BN=128 -> 128x32; col stride wc*(NR*16)).
// BK=64. LDS: 2 x (A 32K + B BN*128B). Swizzle: LDS stays linear, GLOBAL src
// chunk is pre-XORed (rule #21); read applies the same XOR (row&7 == lane&7
// for fragment rows). Phase order (mh,ks)=(0,0),(0,1),(1,0),(1,1): B + A-rows
// {0-63,128-191} of tile v are fully consumed after phase1's closing barrier
// -> phase2 stages tile v+2's B + A-early there; A rows {64-127,192-255}
// free at iter end -> staged at next iter's phase0 (A-late of tile v+1).
// Counted vmcnt at iter top only (never 0 mid-loop). Steady-state queue:
// [B(v)+A_early(v), A_late(v), B(v+1)+A_early(v+1)] -> VMCNT(6)/(4) retires
// exactly tile v's loads.
// ---------------------------------------------------------------------------
extern __shared__ __align__(16) char smem_g256[];

template <int BN, int EP>
__global__ __launch_bounds__(512, 2) void gemm256_k(
    const bf16* __restrict__ A, const bf16* __restrict__ W,
    float* __restrict__ outF, bf16* __restrict__ outB,
    const float* __restrict__ b1, const float* __restrict__ b2,
    const float* __restrict__ resF, const bf16* __restrict__ resB,
    int M, int N, int K) {
    constexpr int NR   = BN / 64;          // n-frags per wave (4 or 2)
    constexpr int NBJ  = BN / 64;          // B stage loads per thread (== NR)
    constexpr int WCS  = NR * 16;          // per-wave column stride (64 or 32)
    constexpr int ASZB = 256 * 64 * 2;     // A-tile bytes
    constexpr int BSZB = BN * 64 * 2;
    constexpr int BUFB = ASZB + BSZB;

    const int tid = threadIdx.x;
    const int wid = tid >> 6, lane = tid & 63;
    const int wr = wid >> 2, wc = wid & 3;
    const int l15 = lane & 15, l4 = lane >> 4;
    const int swz = (lane & 7) << 4;

    // bijective XCD swizzle (gridDim.x % 8 == 0 for all our launches)
    const int nwg = gridDim.x;
    const int bid = ((int)blockIdx.x & 7) * (nwg >> 3) + ((int)blockIdx.x >> 3);
    const int gx = M >> 8;                 // row-blocks; col-major logical order
    const int bm = (bid % gx) * 256;
    const int bn = (bid / gx) * BN;

    const int nt = K >> 6;

    auto stageA = [&](int t, int j) {
        int c = tid + (j << 9);
        int row = c >> 3;
        int cc = (c & 7) ^ (row & 7);
        GLOAD_LDS(A + (size_t)(bm + row) * K + t * 64 + cc * 8,
                  smem_g256 + (size_t)(t & 1) * BUFB + (size_t)c * 16);
    };
    auto stageB = [&](int t, int j) {
        int c = tid + (j << 9);
        int row = c >> 3;
        int cc = (c & 7) ^ (row & 7);
        GLOAD_LDS(W + (size_t)(bn + row) * K + t * 64 + cc * 8,
                  smem_g256 + (size_t)(t & 1) * BUFB + ASZB + (size_t)c * 16);
    };
    auto rdA = [&](int b, int m, int ks) -> short8 {
        int off = b * BUFB + ((wr * 128 + m * 16 + l15) << 7) + (((ks << 6) + (l4 << 4)) ^ swz);
        return *reinterpret_cast<const short8*>(smem_g256 + off);
    };
    auto rdB = [&](int b, int n, int ks) -> short8 {
        int off = b * BUFB + ASZB + ((wc * WCS + n * 16 + l15) << 7) + (((ks << 6) + (l4 << 4)) ^ swz);
        return *reinterpret_cast<const short8*>(smem_g256 + off);
    };

    f32x4 acc[8][NR];
    #pragma unroll
    for (int m = 0; m < 8; m++)
        #pragma unroll
        for (int n = 0; n < NR; n++) acc[m][n] = f32x4{0.f, 0.f, 0.f, 0.f};

    // prologue: tiles 0 and 1 fully staged
    #pragma unroll
    for (int j = 0; j < 4; j++) stageA(0, j);
    #pragma unroll
    for (int j = 0; j < NBJ; j++) stageB(0, j);
    #pragma unroll
    for (int j = 0; j < 4; j++) stageA(1, j);
    #pragma unroll
    for (int j = 0; j < NBJ; j++) stageB(1, j);

    short8 aF[4], bF[NR][2];

    for (int v = 0; v < nt; ++v) {
        const int b = v & 1;
        if (v == 0)            { if constexpr (BN == 256) VMCNT(8); else VMCNT(6); }
        else if (v + 1 < nt)   { if constexpr (BN == 256) VMCNT(6); else VMCNT(4); }
        else                   VMCNT(0);
        BARRIER();   // tile v fully in LDS for every thread

        // ---- phase 0: (mh0, ks0) ----
        #pragma unroll
        for (int m = 0; m < 4; m++) aF[m] = rdA(b, m, 0);
        #pragma unroll
        for (int n = 0; n < NR; n++) bF[n][0] = rdB(b, n, 0);
        if (v >= 1 && v + 1 < nt) { stageA(v + 1, 1); stageA(v + 1, 3); }  // A-late of t+1
        BARRIER();
        __builtin_amdgcn_s_setprio(1);
        #pragma unroll
        for (int m = 0; m < 4; m++)
            #pragma unroll
            for (int n = 0; n < NR; n++)
                acc[m][n] = __builtin_amdgcn_mfma_f32_16x16x32_bf16(aF[m], bF[n][0], acc[m][n], 0, 0, 0);
        __builtin_amdgcn_s_setprio(0);
        BARRIER();

        // ---- phase 1: (mh0, ks1) ----
        #pragma unroll
        for (int m = 0; m < 4; m++) aF[m] = rdA(b, m, 1);
        #pragma unroll
        for (int n = 0; n < NR; n++) bF[n][1] = rdB(b, n, 1);
        BARRIER();
        __builtin_amdgcn_s_setprio(1);
        #pragma unroll
        for (int m = 0; m < 4; m++)
            #pragma unroll
            for (int n = 0; n < NR; n++)
                acc[m][n] = __builtin_amdgcn_mfma_f32_16x16x32_bf16(aF[m], bF[n][1], acc[m][n], 0, 0, 0);
        __builtin_amdgcn_s_setprio(0);
        BARRIER();   // B-tile + A rows {0-63,128-191} of tile v fully consumed

        // ---- phase 2: (mh1, ks0) ----
        #pragma unroll
        for (int m = 0; m < 4; m++) aF[m] = rdA(b, 4 + m, 0);
        if (v + 2 < nt) {            // tile v+2 B + A-early into just-freed regions
            #pragma unroll
            for (int j = 0; j < NBJ; j++) stageB(v + 2, j);
            stageA(v + 2, 0); stageA(v + 2, 2);
        }
        BARRIER();
        __builtin_amdgcn_s_setprio(1);
        #pragma unroll
        for (int m = 0; m < 4; m++)
            #pragma unroll
            for (int n = 0; n < NR; n++)
                acc[4 + m][n] = __builtin_amdgcn_mfma_f32_16x16x32_bf16(aF[m], bF[n][0], acc[4 + m][n], 0, 0, 0);
        __builtin_amdgcn_s_setprio(0);
        BARRIER();

        // ---- phase 3: (mh1, ks1) ----
        #pragma unroll
        for (int m = 0; m < 4; m++) aF[m] = rdA(b, 4 + m, 1);
        BARRIER();
        __builtin_amdgcn_s_setprio(1);
        #pragma unroll
        for (int m = 0; m < 4; m++)
            #pragma unroll
            for (int n = 0; n < NR; n++)
                acc[4 + m][n] = __builtin_amdgcn_mfma_f32_16x16x32_bf16(aF[m], bF[n][1], acc[4 + m][n], 0, 0, 0);
        __builtin_amdgcn_s_setprio(0);
        BARRIER();   // end of iter: remaining A rows of tile v freed
    }

    // epilogue
    const int gc0 = bn + wc * WCS + l15;
    const int gr0 = bm + wr * 128 + l4 * 4;
    #pragma unroll
    for (int m = 0; m < 8; m++)
        #pragma unroll
        for (int n = 0; n < NR; n++) {
            int col = gc0 + n * 16;
            #pragma unroll
            for (int i = 0; i < 4; i++) {
                int row = gr0 + m * 16 + i;
                ep_store<EP>(acc[m][n][i], (size_t)row * N + col, col,
                             outF, outB, b1, b2, resF, resB);
            }
        }
}

// ---------------------------------------------------------------------------
extern "C" void kernel_launch(void* const* d_in, const int* in_sizes, int n_in,
                              void* d_out, int out_size, void* d_ws, size_t ws_size,
                              hipStream_t stream) {
    const int*   x       = (const int*)  d_in[0];
    const float* emb     = (const float*)d_in[1];
    const float* pos_emb = (const float*)d_in[2];
    const float* alpha_W = (const float*)d_in[3];
    const float* alpha_b = (const float*)d_in[4];
    const float* in_W    = (const float*)d_in[5];
    const float* in_b    = (const float*)d_in[6];
    const float* out_W   = (const float*)d_in[7];
    const float* out_b   = (const float*)d_in[8];
    const float* ssm_g   = (const float*)d_in[9];
    const float* ssm_be  = (const float*)d_in[10];
    const float* w1_W    = (const float*)d_in[11];
    const float* w1_b    = (const float*)d_in[12];
    const float* w2_W    = (const float*)d_in[13];
    const float* w2_b    = (const float*)d_in[14];
    const float* w3_W    = (const float*)d_in[15];
    const float* w3_b    = (const float*)d_in[16];
    const float* ff_g    = (const float*)d_in[17];
    const float* ff_be   = (const float*)d_in[18];
    const float* on_g    = (const float*)d_in[19];
    const float* on_be   = (const float*)d_in[20];
    const float* h1_W    = (const float*)d_in[21];
    const float* h1_b    = (const float*)d_in[22];
    const float* h2_W    = (const float*)d_in[23];
    const float* h2_b    = (const float*)d_in[24];
    float* outp = (float*)d_out;
    (void)in_sizes; (void)n_in; (void)out_size; (void)ws_size;

    // allow 128K / 96K dynamic LDS (host-side attribute set; not a stream op)
    hipFuncSetAttribute((const void*)gemm256_k<256, EP_BIAS_BF16>,   hipFuncAttributeMaxDynamicSharedMemorySize, 131072);
    hipFuncSetAttribute((const void*)gemm256_k<256, EP_SILUMUL_BF16>,hipFuncAttributeMaxDynamicSharedMemorySize, 131072);
    hipFuncSetAttribute((const void*)gemm256_k<256, EP_GELU_BF16>,   hipFuncAttributeMaxDynamicSharedMemorySize, 131072);
    hipFuncSetAttribute((const void*)gemm256_k<128, EP_BIAS_RES>,    hipFuncAttributeMaxDynamicSharedMemorySize, 98304);
    hipFuncSetAttribute((const void*)gemm256_k<128, EP_BIAS_F32>,    hipFuncAttributeMaxDynamicSharedMemorySize, 98304);

    char* ws = (char*)d_ws;
    size_t off = 0;
    auto alloc = [&](size_t bytes) { size_t o = off; off += (bytes + 255) & ~(size_t)255; return o; };
    float* h    = (float*)(ws + alloc((size_t)MTOK * D_ * 4));
    bf16*  xn   = (bf16*) (ws + alloc((size_t)MTOK * D_ * 2));
    bf16*  abw  = (bf16*) (ws + alloc((size_t)L_ * 256 * D_ * 2));
    bf16*  outw = (bf16*) (ws + alloc((size_t)L_ * D_ * HN_ * 2));
    bf16*  w1w  = (bf16*) (ws + alloc((size_t)L_ * DFF_ * D_ * 2));
    bf16*  w3w  = (bf16*) (ws + alloc((size_t)L_ * DFF_ * D_ * 2));
    bf16*  w2w  = (bf16*) (ws + alloc((size_t)L_ * D_ * DFF_ * 2));
    bf16*  h1w  = (bf16*) (ws + alloc((size_t)2048 * D_ * 2));
    bf16*  h2w  = (bf16*) (ws + alloc((size_t)D_ * 2048 * 2));
    float* ab   = (float*)(ws + alloc((size_t)MTOK * 256 * 4));
    bf16*  hs   = (bf16*) (ws + alloc((size_t)MTOK * HN_ * 2));
    bf16*  c1   = (bf16*) (ws + alloc((size_t)MTOK * DFF_ * 2));

    auto T = [&](const float* src, bf16* dst, int K, int N) {
        transpose_k<<<dim3(N / 32, K / 32), dim3(32, 8), 0, stream>>>(src, dst, K, N);
    };

    for (int l = 0; l < L_; l++) {
        T(alpha_W + (size_t)l * D_ * HN_,  abw + (size_t)l * 256 * D_,                 D_,  HN_);
        T(in_W    + (size_t)l * D_ * HN_,  abw + (size_t)l * 256 * D_ + (size_t)HN_ * D_, D_, HN_);
        T(out_W   + (size_t)l * HN_ * D_,  outw + (size_t)l * D_ * HN_,                HN_, D_);
        T(w1_W    + (size_t)l * D_ * DFF_, w1w + (size_t)l * DFF_ * D_,                D_,  DFF_);
        T(w3_W    + (size_t)l * D_ * DFF_, w3w + (size_t)l * DFF_ * D_,                D_,  DFF_);
        T(w2_W    + (size_t)l * DFF_ * D_, w2w + (size_t)l * D_ * DFF_,                DFF_, D_);
    }
    T(h1_W, h1w, D_, 2048);
    T(h2_W, h2w, 2048, D_);

    embed_k<<<MTOK, 256, 0, stream>>>(x, emb, pos_emb, h);

    for (int l = 0; l < L_; l++) {
        // ---- SSM block ----
        ln_k<<<MTOK, 256, 0, stream>>>(h, ssm_g + l * D_, ssm_be + l * D_, xn);
        gemm_k<EP_AB><<<dim3(64, 2), 256, 0, stream>>>(
            xn, abw + (size_t)l * 256 * D_, ab, nullptr,
            alpha_b + l * HN_, in_b + l * HN_, nullptr, nullptr, MTOK, 256, D_);
        ssm_scan_k<<<B_ * H_, 256, 0, stream>>>(ab, hs);
        gemm_k<EP_BIAS_RES><<<dim3(64, 8), 256, 0, stream>>>(
            hs, outw + (size_t)l * D_ * HN_, h, nullptr,
            out_b + l * D_, nullptr, h, nullptr, MTOK, D_, HN_);
        // ---- SwiGLU block ----
        ln_k<<<MTOK, 256, 0, stream>>>(h, ff_g + l * D_, ff_be + l * D_, xn);
        gemm256_k<256, EP_BIAS_BF16><<<dim3(32 * (DFF_ / 256)), 512, 131072, stream>>>(
            xn, w1w + (size_t)l * DFF_ * D_, nullptr, c1,
            w1_b + l * DFF_, nullptr, nullptr, nullptr, MTOK, DFF_, D_);
        gemm256_k<256, EP_SILUMUL_BF16><<<dim3(32 * (DFF_ / 256)), 512, 131072, stream>>>(
            xn, w3w + (size_t)l * DFF_ * D_, nullptr, c1,
            w3_b + l * DFF_, nullptr, nullptr, c1, MTOK, DFF_, D_);
        gemm256_k<128, EP_BIAS_RES><<<dim3(32 * (D_ / 128)), 512, 98304, stream>>>(
            c1, w2w + (size_t)l * D_ * DFF_, h, nullptr,
            w2_b + l * D_, nullptr, h, nullptr, MTOK, D_, DFF_);
    }

    // ---- head ----
    ln_k<<<MTOK, 256, 0, stream>>>(h, on_g, on_be, xn);
    gemm256_k<256, EP_GELU_BF16><<<dim3(32 * (2048 / 256)), 512, 131072, stream>>>(
        xn, h1w, nullptr, c1, h1_b, nullptr, nullptr, nullptr, MTOK, 2048, D_);
    gemm256_k<128, EP_BIAS_F32><<<dim3(32 * (C_ / 128)), 512, 98304, stream>>>(
        c1, h2w, outp, nullptr, h2_b, nullptr, nullptr, nullptr, MTOK, C_, 2048);
}